// Round 6
// baseline (1680.720 us; speedup 1.0000x reference)
//
#include <hip/hip_runtime.h>

typedef unsigned short u16;
using bf8   = __attribute__((ext_vector_type(8))) short;  // 8 bf16 (4 VGPRs)
using bf4   = __attribute__((ext_vector_type(4))) short;  // 4 bf16
using f32x4 = __attribute__((ext_vector_type(4))) float;

#define B_ 256
#define T_ 512
#define D_ 64
#define H_ 256
#define Tc_ 64
#define NC_ (T_ / Tc_)
#define GEMMB_ 192   // gemm role blocks; 32+192=224 <= 256 CUs

#define MFMA(a, b, c) __builtin_amdgcn_mfma_f32_16x16x32_bf16(a, b, c, 0, 0, 0)

static __device__ inline u16 f2b(float f) {
    unsigned int u = __float_as_uint(f);
    unsigned int r = (u + 0x7fffu + ((u >> 16) & 1u)) >> 16;
    return (u16)r;
}
static __device__ inline float fast_tanh(float x) {
    float e = __expf(2.f * x);
    return 1.f - 2.f / (e + 1.f);
}
static __device__ inline float fast_sigmoid(float x) {
    return 1.f / (1.f + __expf(-x));
}

// ---------------------------------------------------------------------------
// k_conv: f32 -> bf16 conversion pre-pass (7 weight arrays + x).
// ---------------------------------------------------------------------------
__global__ __launch_bounds__(256) void k_conv(
    const float* __restrict__ W1w, const float* __restrict__ U1w,
    const float* __restrict__ W2w, const float* __restrict__ U2w,
    const float* __restrict__ o1w, const float* __restrict__ o2w,
    const float* __restrict__ gw,  const float* __restrict__ x,
    u16* W1bf, u16* U1bf, u16* W2bf, u16* U2bf,
    u16* o1bf, u16* o2bf, u16* gbf, u16* xbf)
{
    const int a = blockIdx.y;
    const float* src; u16* dst; int n;
    switch (a) {
        case 0: src = W1w; dst = W1bf; n = 16384;   break;
        case 1: src = U1w; dst = U1bf; n = 65536;   break;
        case 2: src = W2w; dst = W2bf; n = 65536;   break;
        case 3: src = U2w; dst = U2bf; n = 65536;   break;
        case 4: src = o1w; dst = o1bf; n = 16384;   break;
        case 5: src = o2w; dst = o2bf; n = 16384;   break;
        case 6: src = gw;  dst = gbf;  n = 131072;  break;
        default: src = x;  dst = xbf;  n = 8388608; break;
    }
    const int i = (blockIdx.x * 256 + threadIdx.x) * 4;
    if (i < n) {
        f32x4 v = *(const f32x4*)(src + i);
        bf4 o;
        o[0] = (short)f2b(v[0]); o[1] = (short)f2b(v[1]);
        o[2] = (short)f2b(v[2]); o[3] = (short)f2b(v[3]);
        *(bf4*)(dst + i) = o;
    }
}

// ---------------------------------------------------------------------------
// h1 role: blocks 0-15. Chunk c. 8 waves, 2 n-chains each. x pre-converted
// to bf16 (xbf), prefetched one step ahead.
// ---------------------------------------------------------------------------
__device__ void h1_role(
    const u16* __restrict__ xbf, const u16* __restrict__ W1,
    const u16* __restrict__ U1, const float* __restrict__ W1b,
    const float* __restrict__ U1b, u16* __restrict__ H1,
    u16* __restrict__ h1state, int c, u16 (*buf)[H_ + 8])
{
    const int g = blockIdx.x;
    const int tid = threadIdx.x;
    const int w = tid >> 6, lane = tid & 63;
    const int col = lane & 15, quad = lane >> 4;
    const int t0 = c * Tc_;

    bf8 u1f[2][8], w1f[2][2];
    float bias[2];
#pragma unroll
    for (int i = 0; i < 2; ++i) {
        const int n = (w * 2 + i) * 16 + col;
#pragma unroll
        for (int kt = 0; kt < 8; ++kt)
            u1f[i][kt] = *(const bf8*)(U1 + (size_t)n * H_ + kt * 32 + quad * 8);
#pragma unroll
        for (int kt = 0; kt < 2; ++kt)
            w1f[i][kt] = *(const bf8*)(W1 + (size_t)n * D_ + kt * 32 + quad * 8);
        bias[i] = W1b[n] + U1b[n];
    }

    if (c == 0) {
        for (int idx = tid; idx < 16 * (H_ + 8); idx += 512)
            ((u16*)buf)[idx] = 0;
    } else {
        const int m = tid >> 5, hb = (tid & 31) * 8;
#pragma unroll
        for (int j = 0; j < 8; ++j)
            buf[m][hb + j] = h1state[(size_t)(g * 16 + m) * H_ + hb + j];
    }
    __syncthreads();

    const u16* xrow = xbf + (size_t)(g * 16 + col) * T_ * D_ + quad * 8;
    bf8 xa0 = *(const bf8*)(xrow + (size_t)t0 * D_);
    bf8 xa1 = *(const bf8*)(xrow + (size_t)t0 * D_ + 32);

#pragma unroll 1
    for (int tt = 0; tt < Tc_; ++tt) {
        const int tn = t0 + (tt + 1 < Tc_ ? tt + 1 : tt);
        bf8 xn0 = *(const bf8*)(xrow + (size_t)tn * D_);
        bf8 xn1 = *(const bf8*)(xrow + (size_t)tn * D_ + 32);

        bf8 haf[8];
#pragma unroll
        for (int kt = 0; kt < 8; ++kt)
            haf[kt] = *(const bf8*)&buf[col][kt * 32 + quad * 8];
        __syncthreads();  // reads done before overwrite

        f32x4 acc[2];
#pragma unroll
        for (int i = 0; i < 2; ++i) {
            acc[i][0] = bias[i]; acc[i][1] = bias[i];
            acc[i][2] = bias[i]; acc[i][3] = bias[i];
        }
#pragma unroll
        for (int kt = 0; kt < 8; ++kt)
#pragma unroll
            for (int i = 0; i < 2; ++i)
                acc[i] = MFMA(haf[kt], u1f[i][kt], acc[i]);
#pragma unroll
        for (int i = 0; i < 2; ++i) {
            acc[i] = MFMA(xa0, w1f[i][0], acc[i]);
            acc[i] = MFMA(xa1, w1f[i][1], acc[i]);
        }

#pragma unroll
        for (int i = 0; i < 2; ++i) {
            const int n = (w * 2 + i) * 16 + col;
#pragma unroll
            for (int r = 0; r < 4; ++r)
                buf[quad * 4 + r][n] = f2b(fast_tanh(acc[i][r]));
        }
        __syncthreads();
        {
            const int m = tid >> 5, hb = (tid & 31) * 8;
            bf8 v0 = *(const bf8*)&buf[m][hb];
            u16* dst = H1 + ((size_t)tt * 256 + g * 16 + m) * H_ + hb;
            *(bf8*)dst = v0;
        }
        xa0 = xn0; xa1 = xn1;
    }
    __syncthreads();
    {
        const int m = tid >> 5, hb = (tid & 31) * 8;
#pragma unroll
        for (int j = 0; j < 8; ++j)
            h1state[(size_t)(g * 16 + m) * H_ + hb + j] = buf[m][hb + j];
    }
}

// ---------------------------------------------------------------------------
// h2 role: blocks 16-31. Chunk ch. Wave-specialized:
//   P-waves (0-3): preact = W2c + U2@h2_prev, tanh, blend, h2 state.
//   G-waves (4-7): gate = sigmoid(G1c + g2@h2), out = O1c + o2@h2 (lag 1).
// u passes G->P via u_lds; h2 f32 state in h2f32 (LDS). 2 barriers/step.
// ---------------------------------------------------------------------------
__device__ void h2_role(
    const u16* __restrict__ U2, const u16* __restrict__ gw,
    const u16* __restrict__ o2w,
    const float* __restrict__ W2c, const float* __restrict__ G1c,
    const float* __restrict__ O1c,
    float* __restrict__ out, float* __restrict__ h2state,
    float* __restrict__ ustate, int ch,
    u16 (*h2buf)[H_ + 8], float* u_lds, float* h2f32)
{
    const int g = blockIdx.x - 16;
    const int tid = threadIdx.x;
    const int w = tid >> 6, lane = tid & 63;
    const int col = lane & 15, quad = lane >> 4;
    const int t0 = ch * Tc_;
    const bool isP = (w < 4);
    const int wp = w & 3;

    // weight fragments: P -> U2 (4 n-tiles), G -> g2 (4 n-tiles) + o2 (1 d-tile)
    bf8 wf[4][8];
    bf8 o2f[8];
    if (isP) {
#pragma unroll
        for (int i = 0; i < 4; ++i)
#pragma unroll
            for (int kt = 0; kt < 8; ++kt)
                wf[i][kt] = *(const bf8*)(U2 + (size_t)((wp * 4 + i) * 16 + col) * H_ +
                                          kt * 32 + quad * 8);
    } else {
#pragma unroll
        for (int i = 0; i < 4; ++i)
#pragma unroll
            for (int kt = 0; kt < 8; ++kt)
                wf[i][kt] = *(const bf8*)(gw + (size_t)((wp * 4 + i) * 16 + col) * (2 * H_) +
                                          H_ + kt * 32 + quad * 8);
#pragma unroll
        for (int kt = 0; kt < 8; ++kt)
            o2f[kt] = *(const bf8*)(o2w + (size_t)(wp * 16 + col) * H_ + kt * 32 + quad * 8);
    }

    // prologue: P seeds h2buf (bf16) + h2f32 (f32) with h2(t0-1)
    if (isP) {
        f32x4 h2p[4];
        if (ch == 0) {
#pragma unroll
            for (int i = 0; i < 4; ++i) {
                h2p[i][0] = 0.f; h2p[i][1] = 0.f; h2p[i][2] = 0.f; h2p[i][3] = 0.f;
            }
        } else {
#pragma unroll
            for (int i = 0; i < 4; ++i)
                h2p[i] = *(const f32x4*)(h2state +
                    (((size_t)g * 16 + (wp * 4 + i)) * 64 + lane) * 4);
        }
#pragma unroll
        for (int i = 0; i < 4; ++i) {
            *(f32x4*)(h2f32 + ((wp * 4 + i) * 64 + lane) * 4) = h2p[i];
            const int n = wp * 64 + i * 16 + col;
#pragma unroll
            for (int r = 0; r < 4; ++r)
                h2buf[quad * 4 + r][n] = f2b(h2p[i][r]);
        }
    }
    __syncthreads();

    // prefetch step 0
    f32x4 w2cn[4];           // P: W2c(0)
    f32x4 g1cn[4], o1cn;     // G: G1c(0), O1c(0)
    if (isP) {
#pragma unroll
        for (int i = 0; i < 4; ++i)
            w2cn[i] = *(const f32x4*)(W2c +
                ((((size_t)g * Tc_) * 16 + (wp * 4 + i)) * 64 + lane) * 4);
    } else {
#pragma unroll
        for (int i = 0; i < 4; ++i)
            g1cn[i] = *(const f32x4*)(G1c +
                ((((size_t)g * Tc_) * 16 + (wp * 4 + i)) * 64 + lane) * 4);
        o1cn = *(const f32x4*)(O1c + ((((size_t)g * Tc_) * 4 + wp) * 64 + lane) * 4);
    }

#pragma unroll 1
    for (int tt = 0; tt <= Tc_; ++tt) {
        f32x4 th[4];
        // ---- A ----
        if (isP) {
            if (tt < Tc_) {
                bf8 h2af[8];
#pragma unroll
                for (int kt = 0; kt < 8; ++kt)
                    h2af[kt] = *(const bf8*)&h2buf[col][kt * 32 + quad * 8];
                f32x4 acc[4];
#pragma unroll
                for (int i = 0; i < 4; ++i) acc[i] = w2cn[i];
                const int tpf = (tt + 1 < Tc_) ? tt + 1 : Tc_ - 1;
#pragma unroll
                for (int i = 0; i < 4; ++i)
                    w2cn[i] = *(const f32x4*)(W2c +
                        ((((size_t)g * Tc_ + tpf) * 16 + (wp * 4 + i)) * 64 + lane) * 4);
#pragma unroll
                for (int kt = 0; kt < 8; ++kt)
#pragma unroll
                    for (int i = 0; i < 4; ++i)
                        acc[i] = MFMA(h2af[kt], wf[i][kt], acc[i]);
#pragma unroll
                for (int i = 0; i < 4; ++i)
#pragma unroll
                    for (int r = 0; r < 4; ++r)
                        th[i][r] = fast_tanh(acc[i][r]);
            }
        } else if (tt >= 1) {
            bf8 h2af[8];
#pragma unroll
            for (int kt = 0; kt < 8; ++kt)
                h2af[kt] = *(const bf8*)&h2buf[col][kt * 32 + quad * 8];
            f32x4 accg[4], acco = o1cn;
#pragma unroll
            for (int i = 0; i < 4; ++i) accg[i] = g1cn[i];
            const int tpf = (tt < Tc_) ? tt : Tc_ - 1;
#pragma unroll
            for (int i = 0; i < 4; ++i)
                g1cn[i] = *(const f32x4*)(G1c +
                    ((((size_t)g * Tc_ + tpf) * 16 + (wp * 4 + i)) * 64 + lane) * 4);
            o1cn = *(const f32x4*)(O1c +
                ((((size_t)g * Tc_ + tpf) * 4 + wp) * 64 + lane) * 4);
#pragma unroll
            for (int kt = 0; kt < 8; ++kt) {
                acco = MFMA(h2af[kt], o2f[kt], acco);
#pragma unroll
                for (int i = 0; i < 4; ++i)
                    accg[i] = MFMA(h2af[kt], wf[i][kt], accg[i]);
            }
            const int t = t0 + tt - 1;
#pragma unroll
            for (int r = 0; r < 4; ++r)
                out[((size_t)(g * 16 + quad * 4 + r) * T_ + t) * D_ + wp * 16 + col] =
                    acco[r];
#pragma unroll
            for (int i = 0; i < 4; ++i)
#pragma unroll
                for (int r = 0; r < 4; ++r)
                    accg[i][r] = fast_sigmoid(accg[i][r]);
            if (tt < Tc_) {
#pragma unroll
                for (int i = 0; i < 4; ++i)
                    *(f32x4*)(u_lds + ((wp * 4 + i) * 64 + lane) * 4) = accg[i];
            } else {
#pragma unroll
                for (int i = 0; i < 4; ++i)
                    *(f32x4*)(ustate +
                        (((size_t)g * 16 + (wp * 4 + i)) * 64 + lane) * 4) = accg[i];
            }
        }
        __syncthreads();  // B: u_lds(tt-1) ready; h2buf reads complete
        // ---- C ----
        if (isP && tt < Tc_) {
            f32x4 uu[4], h2o[4];
            if (tt == 0) {
                if (ch == 0) {
#pragma unroll
                    for (int i = 0; i < 4; ++i) {
                        uu[i][0] = 1.f; uu[i][1] = 1.f; uu[i][2] = 1.f; uu[i][3] = 1.f;
                    }
                } else {
#pragma unroll
                    for (int i = 0; i < 4; ++i)
                        uu[i] = *(const f32x4*)(ustate +
                            (((size_t)g * 16 + (wp * 4 + i)) * 64 + lane) * 4);
                }
            } else {
#pragma unroll
                for (int i = 0; i < 4; ++i)
                    uu[i] = *(const f32x4*)(u_lds + ((wp * 4 + i) * 64 + lane) * 4);
            }
#pragma unroll
            for (int i = 0; i < 4; ++i)
                h2o[i] = *(const f32x4*)(h2f32 + ((wp * 4 + i) * 64 + lane) * 4);
#pragma unroll
            for (int i = 0; i < 4; ++i)
#pragma unroll
                for (int r = 0; r < 4; ++r)
                    h2o[i][r] = uu[i][r] * th[i][r] + (1.f - uu[i][r]) * h2o[i][r];
#pragma unroll
            for (int i = 0; i < 4; ++i) {
                *(f32x4*)(h2f32 + ((wp * 4 + i) * 64 + lane) * 4) = h2o[i];
                const int n = wp * 64 + i * 16 + col;
#pragma unroll
                for (int r = 0; r < 4; ++r)
                    h2buf[quad * 4 + r][n] = f2b(h2o[i][r]);
            }
        }
        __syncthreads();  // D: h2buf/h2f32 = h2(tt)
    }
    // save h2 state (h2f32 holds h2(Tc-1))
    if (isP) {
#pragma unroll
        for (int i = 0; i < 4; ++i)
            *(f32x4*)(h2state + (((size_t)g * 16 + (wp * 4 + i)) * 64 + lane) * 4) =
                *(const f32x4*)(h2f32 + ((wp * 4 + i) * 64 + lane) * 4);
    }
}

// ---------------------------------------------------------------------------
// k_pipe, lag-2 software pipeline across dispatches:
//   blocks 0-15 : h1 of chunk c          (c < NC_)
//   blocks 16-31: h2 of chunk c-2        (c >= 2)
//   blocks 32+  : gemm of chunk c-1      (1 <= c <= NC_)
// ---------------------------------------------------------------------------
__global__ __launch_bounds__(512, 2) void k_pipe(
    const u16* __restrict__ xbf, const u16* __restrict__ W1,
    const u16* __restrict__ U1, const float* __restrict__ W1b,
    const float* __restrict__ U1b, u16* __restrict__ H1w,
    u16* __restrict__ h1state,
    const u16* __restrict__ U2, const u16* __restrict__ gwgt,
    const u16* __restrict__ o2w,
    const float* __restrict__ W2cr, const float* __restrict__ G1cr,
    const float* __restrict__ O1cr,
    float* __restrict__ out, float* __restrict__ h2state,
    float* __restrict__ ustate,
    const u16* __restrict__ H1r, const u16* __restrict__ W2,
    const u16* __restrict__ o1w,
    const float* __restrict__ W2b, const float* __restrict__ U2b,
    const float* __restrict__ gbias, const float* __restrict__ o1b,
    const float* __restrict__ o2b,
    float* __restrict__ W2cw, float* __restrict__ G1cw, float* __restrict__ O1cw,
    int c)
{
    __shared__ __align__(16) u16 h2buf[16][H_ + 8];
    __shared__ __align__(16) float u_lds[4096];
    __shared__ __align__(16) float h2f32[4096];
    if (blockIdx.x < 16) {
        if (c < NC_)
            h1_role(xbf, W1, U1, W1b, U1b, H1w, h1state, c, h2buf);
    } else if (blockIdx.x < 32) {
        if (c >= 2)
            h2_role(U2, gwgt, o2w, W2cr, G1cr, O1cr, out, h2state, ustate, c - 2,
                    h2buf, u_lds, h2f32);
    } else {
        if (c >= 1 && c <= NC_) {
            const int gbk = blockIdx.x - 32;
            const int tid = threadIdx.x;
            const int w = tid >> 6, lane = tid & 63;
            const int col = lane & 15, quad = lane >> 4;
            const int Wv = gbk * 8 + w;
            const int NT = (Tc_ * 256 / 16) * 9;   // 9216 wave-tasks

            for (int task = Wv; task < NT; task += GEMMB_ * 8) {
                const int mt = task & 1023, ny = task >> 10;
                const int mrow = mt * 16;

                f32x4 acc[4];
#pragma unroll
                for (int i = 0; i < 4; ++i) { acc[i][0]=0.f; acc[i][1]=0.f; acc[i][2]=0.f; acc[i][3]=0.f; }

#pragma unroll
                for (int kt = 0; kt < 8; ++kt) {
                    const int k = kt * 32 + quad * 8;
                    bf8 af = *(const bf8*)(H1r + (size_t)(mrow + col) * H_ + k);
#pragma unroll
                    for (int i = 0; i < 4; ++i) {
                        const int n = ny * 64 + i * 16 + col;
                        const u16* bp;
                        if (n < 256)      bp = W2   + (size_t)n * H_ + k;
                        else if (n < 512) bp = gwgt + (size_t)(n - 256) * (2 * H_) + k;
                        else              bp = o1w  + (size_t)(n - 512) * H_ + k;
                        bf8 bfv = *(const bf8*)bp;
                        acc[i] = MFMA(af, bfv, acc[i]);
                    }
                }

                const int tt = mrow >> 8;
                const int g  = (mrow & 255) >> 4;
#pragma unroll
                for (int i = 0; i < 4; ++i) {
                    const int n = ny * 64 + i * 16 + col;
                    float bias;
                    if (n < 256)      bias = W2b[n] + U2b[n];
                    else if (n < 512) bias = gbias[n - 256];
                    else              bias = o1b[n - 512] + o2b[n - 512];
                    f32x4 v;
#pragma unroll
                    for (int r = 0; r < 4; ++r) v[r] = acc[i][r] + bias;
                    const int nt = ny * 4 + i;
                    if (nt < 16) {
                        size_t idx = ((((size_t)g * Tc_ + tt) * 16 + nt) * 64 + lane) * 4;
                        *(f32x4*)(W2cw + idx) = v;
                    } else if (nt < 32) {
                        size_t idx = ((((size_t)g * Tc_ + tt) * 16 + (nt - 16)) * 64 + lane) * 4;
                        *(f32x4*)(G1cw + idx) = v;
                    } else {
                        size_t idx = ((((size_t)g * Tc_ + tt) * 4 + (nt - 32)) * 64 + lane) * 4;
                        *(f32x4*)(O1cw + idx) = v;
                    }
                }
            }
        }
    }
}

// ---------------------------------------------------------------------------
extern "C" void kernel_launch(void* const* d_in, const int* in_sizes, int n_in,
                              void* d_out, int out_size, void* d_ws, size_t ws_size,
                              hipStream_t stream)
{
    const float* x   = (const float*)d_in[0];
    const float* W1w = (const float*)d_in[1];
    const float* W1b = (const float*)d_in[2];
    const float* U1w = (const float*)d_in[3];
    const float* U1b = (const float*)d_in[4];
    const float* W2w = (const float*)d_in[5];
    const float* W2b = (const float*)d_in[6];
    const float* U2w = (const float*)d_in[7];
    const float* U2b = (const float*)d_in[8];
    const float* o1w = (const float*)d_in[9];
    const float* o1b = (const float*)d_in[10];
    const float* o2w = (const float*)d_in[11];
    const float* o2b = (const float*)d_in[12];
    const float* gw  = (const float*)d_in[13];
    const float* gb  = (const float*)d_in[14];
    float* out = (float*)d_out;
    (void)in_sizes; (void)n_in; (void)out_size; (void)ws_size;

    char* p = (char*)d_ws;
    u16* W1bf = (u16*)p; p += 16384 * 2;
    u16* U1bf = (u16*)p; p += 65536 * 2;
    u16* W2bf = (u16*)p; p += 65536 * 2;
    u16* U2bf = (u16*)p; p += 65536 * 2;
    u16* o1bf = (u16*)p; p += 16384 * 2;
    u16* o2bf = (u16*)p; p += 16384 * 2;
    u16* gbf  = (u16*)p; p += 131072 * 2;
    u16* xbf  = (u16*)p; p += (size_t)8388608 * 2;
    u16* H1[2]; float* W2c[2]; float* G1c[2]; float* O1c[2];
    for (int pa = 0; pa < 2; ++pa) {
        H1[pa]  = (u16*)p;   p += (size_t)Tc_ * 131072;   // Tc*256*256 bf16
        W2c[pa] = (float*)p; p += (size_t)Tc_ * 262144;   // Tc*256*256 f32
        G1c[pa] = (float*)p; p += (size_t)Tc_ * 262144;
        O1c[pa] = (float*)p; p += (size_t)Tc_ * 65536;    // Tc*256*64 f32
    }
    u16* h1s   = (u16*)p;  p += 131072;
    float* h2s = (float*)p; p += 262144;
    float* us  = (float*)p;

    k_conv<<<dim3(8192, 8), 256, 0, stream>>>(W1w, U1w, W2w, U2w, o1w, o2w, gw, x,
                                              W1bf, U1bf, W2bf, U2bf, o1bf, o2bf,
                                              gbf, xbf);

    // lag-2 pipeline: dispatch c = { h1(c), gemm(c-1), h2(c-2) }
    for (int c = 0; c <= NC_ + 1; ++c) {
        const int pw = c & 1;         // h1 writes chunk c
        const int pg = (c + 1) & 1;   // gemm: chunk c-1  (reads H1[pg], writes C[pg])
        const int ph = c & 1;         // h2: chunk c-2    (reads C[ph])
        k_pipe<<<32 + GEMMB_, 512, 0, stream>>>(
            xbf, W1bf, U1bf, W1b, U1b, H1[pw], h1s,
            U2bf, gbf, o2bf, W2c[ph], G1c[ph], O1c[ph],
            out, h2s, us,
            H1[pg], W2bf, o1bf, W2b, U2b, gb, o1b, o2b,
            W2c[pg], G1c[pg], O1c[pg], c);
    }
}